// Round 1
// baseline (104.857 us; speedup 1.0000x reference)
//
#include <hip/hip_runtime.h>
#include <math.h>

#define NB 11
#define PAD 5
#define DIM 128
#define NN 121        // NB*NB
#define S_TOT 484     // HEADS*NN
#define IMG 64
#define TILE 8        // pixels per block (x-contiguous)
#define SCP 520       // sc_bf row stride (bf16), 16B-aligned, >= 512
#define PSCP 488      // psc row stride (f32)
#define UCOLS 18      // union columns: j_abs+5 for 8 pixels
#define UCELLS 198    // 11*18 union cells
#define NT_KV 50      // ceil(792/16) N-tiles in union kv GEMM
#define NT_POS 31     // N-tiles in pos GEMM (496 >= 484)
#define LN_EPS 1e-5f

typedef __attribute__((ext_vector_type(8))) short bf16x8;
typedef __attribute__((ext_vector_type(4))) float f32x4;

static __device__ __forceinline__ unsigned short f2bf(float f) {
    unsigned u = __float_as_uint(f);
    u += 0x7FFF + ((u >> 16) & 1);          // round-to-nearest-even
    return (unsigned short)(u >> 16);
}

// Tiny prologue, 40 blocks x 256 threads (4 work-units each):
// blocks [0,32): W B-frag; [32,40): posB. (pkvb staging eliminated: nca
// reads fp32 kv directly with inline bf16 convert + bounds-zero.)
__global__ __launch_bounds__(256) void prep_kernel(
    const float* __restrict__ w, const float* __restrict__ pos,
    unsigned short* __restrict__ wfrag, unsigned short* __restrict__ posB)
{
    const int blk  = blockIdx.x;
    const int lane = threadIdx.x & 63;
    const int sub  = threadIdx.x >> 6;     // unit within block, 0..3
    if (blk < 32) {
        const int idx = blk * 4 + sub;     // 0..127
        const int t   = idx & 15;
        const int n   = ((idx >> 4) << 4) + (lane & 15);
        const int kb  = t * 32 + ((lane >> 4) << 3);
        unsigned short v[8];
        #pragma unroll
        for (int j = 0; j < 8; ++j) {
            const int k = kb + j;
            v[j] = (k < S_TOT) ? f2bf(w[(size_t)k * DIM + n]) : (unsigned short)0;
        }
        *(uint4*)(wfrag + (((size_t)idx * 64 + lane) << 3)) = *(const uint4*)v;
    } else {
        // posB[(nt*64+lane)*8+j] = pos4[s=16nt+(lane&15)][(lane>>4)*8+j],
        // pos4[s][d] = pos[s>>2][32*(s&3)+d]; zero rows p>120.
        const int nt = (blk - 32) * 4 + sub;
        if (nt < NT_POS) {
            const int m    = lane & 15, quad = lane >> 4;
            const int p    = 4 * nt + (m >> 2);
            const int r    = m & 3;
            unsigned short v[8];
            #pragma unroll
            for (int j = 0; j < 8; ++j)
                v[j] = (p <= 120) ? f2bf(pos[(size_t)p * DIM + 32 * r + 8 * quad + j])
                                  : (unsigned short)0;
            *(uint4*)(posB + (((size_t)nt * 64 + lane) << 3)) = *(const uint4*)v;
        }
    }
}

// Single-arg launch bounds ONLY: (512,8)/(256,8) capped VGPR at 32 and spilled.
__global__ __launch_bounds__(512) void nca_kernel(
    const float* __restrict__ q, const float* __restrict__ kv,
    const unsigned short* __restrict__ posB, const unsigned short* __restrict__ wfrag,
    const float* __restrict__ bias, const float* __restrict__ gam,
    const float* __restrict__ bet, float* __restrict__ out)
{
    // XCD-bijective swizzle: 1024 = 8 XCDs x 128; consecutive hw blocks on one
    // XCD become a contiguous band of 128 tiles (16 image rows) -> kv band
    // (~0.9 MB fp32) fits the XCD-private 4 MB L2.
    const int g    = blockIdx.x;
    const int tile = ((g & 7) << 7) | (g >> 3);
    const int pix0 = tile * TILE;
    const int x0 = pix0 & 63;
    const int y  = (pix0 >> 6) & 63;
    const int b  = pix0 >> 12;
    const int tid = threadIdx.x;

    __shared__ float qs[TILE][DIM];                          // 4 KB
    __shared__ float psc[TILE][PSCP];                        // 15.6 KB fp32 pos-scores
    __shared__ __align__(16) unsigned short sc_bf[TILE][SCP];// 8.3 KB bf16 scores
    __shared__ float mlp[TILE][DIM];                         // 4 KB

    // ---- stage q; zero sc pad [484,520) (phase B reads K up to 512) ----
    for (int i = tid; i < TILE * DIM; i += 512)
        qs[i >> 7][i & 127] = q[(size_t)pix0 * DIM + i];
    for (int i = tid; i < TILE * (SCP - S_TOT); i += 512)
        sc_bf[i / (SCP - S_TOT)][S_TOT + i % (SCP - S_TOT)] = 0;

    // ---- phase A: transposed score GEMMs. A = q rows: M = 16 = (px,h)
    // pairs: A[m][k] = q[4*mt+(m>>2)][32*(m&3)+k]. D row m=quad*4+reg ->
    // px = 4*mt+quad, h = reg.
    // Pass 1 (pos): B cols = s-slots (posB);  psc[px][s] = D[(px,h(s))][s].
    // Pass 2 (kv):  B cols = union cells (11 x 18) x 4 r-slices, shared by
    // all 8 pixels; score[px][s] = D[(px,h)][slot] + psc, s = 44i+4(u-px)+r.
    // Pass 2 B-frags come straight from fp32 kv (2x float4 + f2bf x8);
    // OOB cells -> 0, which IS the reference's zero-pad semantics.
    {
        const int wid  = tid >> 6;
        const int lane = tid & 63;
        const int n    = lane & 15, quad = lane >> 4;
        const int mt   = wid & 1;          // pixel half
        const int w4   = wid >> 1;         // tile-stride offset 0..3
        const int pxl  = 4 * mt + quad;    // this lane's pixel

        // A-frag (one-time): row m = n, k = 8*quad+j
        const float* qa = q + ((size_t)(pix0 + 4 * mt + (n >> 2))) * DIM
                            + 32 * (n & 3) + 8 * quad;
        const float4 fa0 = *(const float4*)qa;
        const float4 fa1 = *(const float4*)(qa + 4);
        unsigned short aq_[8] = {f2bf(fa0.x), f2bf(fa0.y), f2bf(fa0.z), f2bf(fa0.w),
                                 f2bf(fa1.x), f2bf(fa1.y), f2bf(fa1.z), f2bf(fa1.w)};
        const bf16x8 Aq = *(const bf16x8*)aq_;

        // ---- pass 1: pos GEMM -> psc (fp32) ----
        {
            const unsigned short* pb = posB + ((size_t)lane << 3);
            int nt = w4;
            bf16x8 Bc = *(const bf16x8*)(pb + (size_t)nt * 512);
            while (nt < NT_POS) {
                const int ntn = nt + 4;
                bf16x8 Bn = Bc;
                if (ntn < NT_POS) Bn = *(const bf16x8*)(pb + (size_t)ntn * 512);
                f32x4 acc = {0.f, 0.f, 0.f, 0.f};
                acc = __builtin_amdgcn_mfma_f32_16x16x32_bf16(Aq, Bc, acc, 0, 0, 0);
                const int s = 16 * nt + n;
                if (s < S_TOT) {
                    const int h = (271 * s) >> 15;   // s/121, exact for s<512
                    const float v = (h == 0) ? acc[0] : (h == 1) ? acc[1]
                                  : (h == 2) ? acc[2] : acc[3];
                    psc[pxl][s] = v;
                }
                Bc = Bn; nt = ntn;
            }
        }
        __syncthreads();

        // ---- pass 2: union kv GEMM -> sc_bf (adds psc, one bf16 round) ----
        {
            const int r  = n & 3;
            const int co = 32 * r + 8 * quad;
            const float* kvb = kv + (size_t)b * IMG * IMG * DIM + co;
            int c = 4 * w4 + (n >> 2);     // union cell (<=15 -> i=0,u=c)
            int i = 0, u = c;
            float4 k0 = make_float4(0.f, 0.f, 0.f, 0.f), k1 = k0;
            {
                const int ky = y + i - PAD, kx = x0 + u - PAD;
                if ((unsigned)ky < (unsigned)IMG && (unsigned)kx < (unsigned)IMG) {
                    const float* p = kvb + (size_t)(ky * IMG + kx) * DIM;
                    k0 = *(const float4*)p; k1 = *(const float4*)(p + 4);
                }
            }
            int nt = w4;
            while (nt < NT_KV) {
                // advance per-lane cell by 16 (nt += 4), clamp pad cells
                int cn = c + 16, in_ = i, un = u + 16;
                if (un >= UCOLS) { un -= UCOLS; ++in_; }
                if (cn > UCELLS - 1) { in_ = 10; un = UCOLS - 1; }
                float4 n0 = make_float4(0.f, 0.f, 0.f, 0.f), n1 = n0;
                if (nt + 4 < NT_KV) {
                    const int ky = y + in_ - PAD, kx = x0 + un - PAD;
                    if ((unsigned)ky < (unsigned)IMG && (unsigned)kx < (unsigned)IMG) {
                        const float* p = kvb + (size_t)(ky * IMG + kx) * DIM;
                        n0 = *(const float4*)p; n1 = *(const float4*)(p + 4);
                    }
                }
                unsigned short bv[8] = {f2bf(k0.x), f2bf(k0.y), f2bf(k0.z), f2bf(k0.w),
                                        f2bf(k1.x), f2bf(k1.y), f2bf(k1.z), f2bf(k1.w)};
                const bf16x8 Bc = *(const bf16x8*)bv;
                f32x4 acc = {0.f, 0.f, 0.f, 0.f};
                acc = __builtin_amdgcn_mfma_f32_16x16x32_bf16(Aq, Bc, acc, 0, 0, 0);
                const int jr = u - pxl;               // j_rel
                if ((unsigned)jr < 11u) {
                    const int s = 44 * i + 4 * jr + r;
                    const int h = (271 * s) >> 15;
                    const float v = ((h == 0) ? acc[0] : (h == 1) ? acc[1]
                                   : (h == 2) ? acc[2] : acc[3]) + psc[pxl][s];
                    sc_bf[pxl][s] = f2bf(v);
                }
                k0 = n0; k1 = n1; c = cn; i = in_; u = un; nt += 4;
            }
        }
    }
    __syncthreads();

    // ---- phase B: MFMA MLP: wave = n-tile of 16 channels, K=512 ----
    {
        const int wv   = tid >> 6;
        const int lane = tid & 63;
        const int m    = lane & 15;
        const int quad = lane >> 4;
        const unsigned short* bfr = wfrag + (((size_t)(wv * 16) * 64 + lane) << 3);
        const unsigned short* ap  = &sc_bf[m & 7][quad * 8];
        f32x4 acc = {0.f, 0.f, 0.f, 0.f};
        bf16x8 b0 = *(const bf16x8*)(bfr);
        bf16x8 b1 = *(const bf16x8*)(bfr + 512);
        bf16x8 b2 = *(const bf16x8*)(bfr + 1024);
        bf16x8 b3 = *(const bf16x8*)(bfr + 1536);
        #pragma unroll
        for (int t = 0; t < 16; ++t) {
            const bf16x8 a = *(const bf16x8*)(ap + t * 32);
            bf16x8 bn = b3;
            if (t + 4 < 16) bn = *(const bf16x8*)(bfr + (t + 4) * 512);
            acc = __builtin_amdgcn_mfma_f32_16x16x32_bf16(a, b0, acc, 0, 0, 0);
            b0 = b1; b1 = b2; b2 = b3; b3 = bn;
        }
        if (quad < 2) {
            #pragma unroll
            for (int reg = 0; reg < 4; ++reg)
                mlp[quad * 4 + reg][wv * 16 + m] = acc[reg];
        }
    }
    __syncthreads();

    // ---- epilogue: bias, exact GELU, residual ----
    for (int idx = tid; idx < TILE * DIM; idx += 512) {
        const int pix = idx >> 7, cc = idx & 127;
        const float v = mlp[pix][cc] + bias[cc];
        const float gl = 0.5f * v * (1.f + erff(v * 0.70710678118654752f));
        qs[pix][cc] += gl;               // x = q + gelu(mlp)
    }
    __syncthreads();

    // ---- LayerNorm: wave wid owns pixel wid ----
    {
        const int lane = tid & 63, wid = tid >> 6;
        const float v0 = qs[wid][lane], v1 = qs[wid][lane + 64];
        float sum = v0 + v1;
        #pragma unroll
        for (int off = 1; off < 64; off <<= 1) sum += __shfl_xor(sum, off, 64);
        const float mean = sum * (1.f / 128.f);
        const float d0 = v0 - mean, d1 = v1 - mean;
        float sq = d0 * d0 + d1 * d1;
        #pragma unroll
        for (int off = 1; off < 64; off <<= 1) sq += __shfl_xor(sq, off, 64);
        const float rstd = rsqrtf(sq * (1.f / 128.f) + LN_EPS);
        float* op = out + (size_t)(pix0 + wid) * DIM;
        op[lane]      = d0 * rstd * gam[lane]      + bet[lane];
        op[lane + 64] = d1 * rstd * gam[lane + 64] + bet[lane + 64];
    }
}

// Fallback (fp32, bounds-checked, no workspace).
__global__ __launch_bounds__(512) void nca_kernel_nopad(
    const float* __restrict__ q, const float* __restrict__ kvsrc,
    const float* __restrict__ pos, const float* __restrict__ w,
    const float* __restrict__ bias, const float* __restrict__ gam,
    const float* __restrict__ bet, float* __restrict__ out)
{
    const int tile = blockIdx.x;
    const int pix0 = tile * TILE;
    const int x0 = pix0 & 63;
    const int y  = (pix0 >> 6) & 63;
    const int b  = pix0 >> 12;
    const int tid = threadIdx.x;

    __shared__ float qs[TILE][DIM];
    __shared__ float sc[S_TOT][TILE];
    __shared__ float part[4][TILE][DIM];

    for (int i = tid; i < TILE * DIM; i += 512)
        qs[i >> 7][i & 127] = q[(size_t)pix0 * DIM + i];
    __syncthreads();

    {
        const int pix = tid >> 6;
        const int grp = (tid >> 4) & 3;
        const int l16 = tid & 15;
        const int r   = l16 >> 2;
        const int dq  = 8 * (l16 & 3);
        const int ch  = 8 * l16;
        const int xpix = x0 + pix;
        int p = grp, i = 0, j = grp;
        int h = 0, rem = 4 * grp + r;
        const float* kvb  = kvsrc + (size_t)b * IMG * IMG * DIM + ch;
        const float* posb = pos + ch;
        float4 q0 = *(const float4*)(&qs[pix][dq]);
        float4 q1 = *(const float4*)(&qs[pix][dq + 4]);
        for (int it = 0; it < 31; ++it) {
            if (p <= 120) {
                float4 k0 = make_float4(0.f,0.f,0.f,0.f), k1 = k0;
                const int ky = y + i - PAD, kx = xpix + j - PAD;
                if (((unsigned)ky < (unsigned)IMG) && ((unsigned)kx < (unsigned)IMG)) {
                    const float* kp = kvb + (size_t)(ky * IMG + kx) * DIM;
                    k0 = *(const float4*)(kp);
                    k1 = *(const float4*)(kp + 4);
                }
                const float4 p0 = *(const float4*)(posb + (size_t)p * DIM);
                const float4 p1 = *(const float4*)(posb + (size_t)p * DIM + 4);
                float t = (k0.x + p0.x) * q0.x + (k0.y + p0.y) * q0.y
                        + (k0.z + p0.z) * q0.z + (k0.w + p0.w) * q0.w
                        + (k1.x + p1.x) * q1.x + (k1.y + p1.y) * q1.y
                        + (k1.z + p1.z) * q1.z + (k1.w + p1.w) * q1.w;
                t += __shfl_xor(t, 1, 64);
                t += __shfl_xor(t, 2, 64);
                if ((l16 & 3) == 0) sc[4 * p + r][pix] = t;
            }
            p += 4; j += 4;
            if (j >= NB) { j -= NB; ++i; }
            rem += 16;
            if (rem >= NN) {
                rem -= NN; ++h;
                q0 = *(const float4*)(&qs[pix][h * 32 + dq]);
                q1 = *(const float4*)(&qs[pix][h * 32 + dq + 4]);
            }
        }
    }
    __syncthreads();

    {
        const int l  = tid & 63;
        const int wv = tid >> 6;
        const int g  = wv >> 1;
        const int ph = wv & 1;
        const float* wc  = w + (size_t)(g * NN) * DIM + l;
        const float* scp = &sc[g * NN][ph * 4];
        float a00=0,a01=0,a10=0,a11=0,a20=0,a21=0,a30=0,a31=0;
        #pragma unroll 2
        for (int s = 0; s < NN; ++s) {
            const float4 sv = *(const float4*)(scp + s * 8);
            const float w0 = wc[(size_t)s * DIM];
            const float w1 = wc[(size_t)s * DIM + 64];
            a00 += sv.x * w0; a01 += sv.x * w1;
            a10 += sv.y * w0; a11 += sv.y * w1;
            a20 += sv.z * w0; a21 += sv.z * w1;
            a30 += sv.w * w0; a31 += sv.w * w1;
        }
        const int pb = ph * 4;
        part[g][pb+0][l] = a00; part[g][pb+0][l+64] = a01;
        part[g][pb+1][l] = a10; part[g][pb+1][l+64] = a11;
        part[g][pb+2][l] = a20; part[g][pb+2][l+64] = a21;
        part[g][pb+3][l] = a30; part[g][pb+3][l+64] = a31;
    }
    __syncthreads();

    for (int idx = tid; idx < TILE * DIM; idx += 512) {
        const int pix = idx >> 7, cc = idx & 127;
        float v = part[0][pix][cc] + part[1][pix][cc]
                + part[2][pix][cc] + part[3][pix][cc] + bias[cc];
        const float gl = 0.5f * v * (1.f + erff(v * 0.70710678118654752f));
        qs[pix][cc] += gl;
    }
    __syncthreads();

    {
        const int lane = tid & 63, wid = tid >> 6;
        const float v0 = qs[wid][lane], v1 = qs[wid][lane + 64];
        float sum = v0 + v1;
        #pragma unroll
        for (int off = 1; off < 64; off <<= 1) sum += __shfl_xor(sum, off, 64);
        const float mean = sum * (1.f / 128.f);
        const float d0 = v0 - mean, d1 = v1 - mean;
        float sq = d0 * d0 + d1 * d1;
        #pragma unroll
        for (int off = 1; off < 64; off <<= 1) sq += __shfl_xor(sq, off, 64);
        const float rstd = rsqrtf(sq * (1.f / 128.f) + LN_EPS);
        float* op = out + (size_t)(pix0 + wid) * DIM;
        op[lane]      = d0 * rstd * gam[lane]      + bet[lane];
        op[lane + 64] = d1 * rstd * gam[lane + 64] + bet[lane + 64];
    }
}

extern "C" void kernel_launch(void* const* d_in, const int* in_sizes, int n_in,
                              void* d_out, int out_size, void* d_ws, size_t ws_size,
                              hipStream_t stream) {
    const float* q    = (const float*)d_in[0];
    const float* kv   = (const float*)d_in[1];
    const float* pos  = (const float*)d_in[2];
    const float* w    = (const float*)d_in[3];
    const float* bias = (const float*)d_in[4];
    const float* gam  = (const float*)d_in[5];
    const float* bet  = (const float*)d_in[6];
    float* out = (float*)d_out;

    const int n_blocks = 2 * IMG * IMG / TILE;   // 1024
    const size_t wfrag_bytes = (size_t)8 * 16 * 64 * 8 * sizeof(unsigned short);       // 131,072
    const size_t posB_bytes  = (size_t)NT_POS * 64 * 8 * sizeof(unsigned short);       // 31,744

    if (ws_size >= wfrag_bytes + posB_bytes) {
        unsigned short* wfrag = (unsigned short*)d_ws;
        unsigned short* posB  = (unsigned short*)((char*)d_ws + wfrag_bytes);
        prep_kernel<<<40, 256, 0, stream>>>(w, pos, wfrag, posB);
        nca_kernel<<<n_blocks, 512, 0, stream>>>(q, kv, posB, wfrag, bias, gam, bet, out);
    } else {
        nca_kernel_nopad<<<n_blocks, 512, 0, stream>>>(q, kv, pos, w, bias, gam, bet, out);
    }
}

// Round 2
// 91.202 us; speedup vs baseline: 1.1497x; 1.1497x over previous
//
#include <hip/hip_runtime.h>
#include <math.h>

#define NB 11
#define PAD 5
#define DIM 128
#define NN 121        // NB*NB
#define S_TOT 484     // HEADS*NN
#define IMG 64
#define TILE 8        // pixels per block (x-contiguous)
#define PDIM 74       // IMG + 2*PAD
#define SCP 520       // sc_bf row stride (bf16), 16B-aligned, >= 512
#define PSCP 488      // psc row stride (f32)
#define UCOLS 18      // union columns: j_abs+5 for 8 pixels
#define UCELLS 198    // 11*18 union cells
#define NT_KV 50      // ceil(792/16) N-tiles in union kv GEMM
#define NT_POS 31     // N-tiles in pos GEMM (496 >= 484)
#define NPAD (2 * PDIM * PDIM)   // 10952 padded kv rows
#define KVB ((NPAD + 3) / 4)     // 2738 kv prep blocks (4 rows each)
#define LN_EPS 1e-5f

typedef __attribute__((ext_vector_type(8))) short bf16x8;
typedef __attribute__((ext_vector_type(4))) float f32x4;

static __device__ __forceinline__ unsigned short f2bf(float f) {
    unsigned u = __float_as_uint(f);
    u += 0x7FFF + ((u >> 16) & 1);          // round-to-nearest-even
    return (unsigned short)(u >> 16);
}

// Fused prologue, 256-thread blocks (4 work-units each):
// blocks [0,KVB): pad+bf16 kv rows; [KVB,KVB+32): W B-frag; [KVB+32,+8): posB.
__global__ __launch_bounds__(256) void prep_kernel(
    const float* __restrict__ kv, const float* __restrict__ w,
    const float* __restrict__ pos, unsigned short* __restrict__ pkvb,
    unsigned short* __restrict__ wfrag, unsigned short* __restrict__ posB)
{
    const int blk  = blockIdx.x;
    const int lane = threadIdx.x & 63;
    const int sub  = threadIdx.x >> 6;     // unit within block, 0..3
    if (blk < KVB) {
        const int row = blk * 4 + sub;     // padded row index
        if (row < NPAD) {
            const int b  = row / (PDIM * PDIM);
            const int rr = row - b * PDIM * PDIM;
            const int py = rr / PDIM;
            const int px = rr - py * PDIM;
            const int ky = py - PAD, kx = px - PAD;
            unsigned v = 0;
            if ((unsigned)ky < (unsigned)IMG && (unsigned)kx < (unsigned)IMG) {
                const float2 f = *(const float2*)(kv + (((size_t)b * IMG + ky) * IMG + kx) * DIM + 2 * lane);
                v = (unsigned)f2bf(f.x) | ((unsigned)f2bf(f.y) << 16);
            }
            *(unsigned*)(pkvb + (size_t)row * DIM + 2 * lane) = v;
        }
    } else if (blk < KVB + 32) {
        const int idx = (blk - KVB) * 4 + sub;   // 0..127
        const int t   = idx & 15;
        const int n   = ((idx >> 4) << 4) + (lane & 15);
        const int kb  = t * 32 + ((lane >> 4) << 3);
        unsigned short v[8];
        #pragma unroll
        for (int j = 0; j < 8; ++j) {
            const int k = kb + j;
            v[j] = (k < S_TOT) ? f2bf(w[(size_t)k * DIM + n]) : (unsigned short)0;
        }
        *(uint4*)(wfrag + (((size_t)idx * 64 + lane) << 3)) = *(const uint4*)v;
    } else {
        // posB[(nt*64+lane)*8+j] = pos4[s=16nt+(lane&15)][(lane>>4)*8+j],
        // pos4[s][d] = pos[s>>2][32*(s&3)+d]; zero rows p>120.
        const int nt = (blk - KVB - 32) * 4 + sub;
        if (nt < NT_POS) {
            const int m    = lane & 15, quad = lane >> 4;
            const int p    = 4 * nt + (m >> 2);
            const int r    = m & 3;
            unsigned short v[8];
            #pragma unroll
            for (int j = 0; j < 8; ++j)
                v[j] = (p <= 120) ? f2bf(pos[(size_t)p * DIM + 32 * r + 8 * quad + j])
                                  : (unsigned short)0;
            *(uint4*)(posB + (((size_t)nt * 64 + lane) << 3)) = *(const uint4*)v;
        }
    }
}

// Single-arg launch bounds ONLY: (512,8)/(256,8) capped VGPR at 32 and spilled.
__global__ __launch_bounds__(512) void nca_kernel(
    const float* __restrict__ q, const unsigned short* __restrict__ pkvb,
    const unsigned short* __restrict__ posB, const unsigned short* __restrict__ wfrag,
    const float* __restrict__ bias, const float* __restrict__ gam,
    const float* __restrict__ bet, float* __restrict__ out)
{
    // XCD-bijective swizzle: 1024 = 8 XCDs x 128; consecutive hw blocks on one
    // XCD become a contiguous band of 128 tiles (16 image rows) -> pkvb band
    // (~0.5 MB) + wfrag (128 KB) fit the XCD-private 4 MB L2.
    const int g    = blockIdx.x;
    const int tile = ((g & 7) << 7) | (g >> 3);
    const int pix0 = tile * TILE;
    const int x0 = pix0 & 63;
    const int y  = (pix0 >> 6) & 63;
    const int b  = pix0 >> 12;
    const int tid = threadIdx.x;

    __shared__ float qs[TILE][DIM];                          // 4 KB
    __shared__ float psc[TILE][PSCP];                        // 15.6 KB fp32 pos-scores
    __shared__ __align__(16) unsigned short sc_bf[TILE][SCP];// 8.3 KB bf16 scores
    __shared__ float mlp[TILE][DIM];                         // 4 KB

    // ---- stage q; zero sc pad [484,520) (phase B reads K up to 512) ----
    for (int i = tid; i < TILE * DIM; i += 512)
        qs[i >> 7][i & 127] = q[(size_t)pix0 * DIM + i];
    for (int i = tid; i < TILE * (SCP - S_TOT); i += 512)
        sc_bf[i / (SCP - S_TOT)][S_TOT + i % (SCP - S_TOT)] = 0;

    // ---- phase A: transposed score GEMMs. A = q rows: M = 16 = (px,h)
    // pairs: A[m][k] = q[4*mt+(m>>2)][32*(m&3)+k]. D row m=quad*4+reg ->
    // px = 4*mt+quad, h = reg.
    // Pass 1 (pos): B cols = s-slots (posB);  psc[px][s] = D[(px,h(s))][s].
    // Pass 2 (kv):  B cols = union cells (11 x 18) x 4 r-slices, shared by
    // all 8 pixels; score[px][s] = D[(px,h)][slot] + psc, s = 44i+4(u-px)+r.
    {
        const int wid  = tid >> 6;
        const int lane = tid & 63;
        const int n    = lane & 15, quad = lane >> 4;
        const int mt   = wid & 1;          // pixel half
        const int w4   = wid >> 1;         // tile-stride offset 0..3
        const int pxl  = 4 * mt + quad;    // this lane's pixel

        // A-frag (one-time): row m = n, k = 8*quad+j
        const float* qa = q + ((size_t)(pix0 + 4 * mt + (n >> 2))) * DIM
                            + 32 * (n & 3) + 8 * quad;
        const float4 fa0 = *(const float4*)qa;
        const float4 fa1 = *(const float4*)(qa + 4);
        unsigned short aq_[8] = {f2bf(fa0.x), f2bf(fa0.y), f2bf(fa0.z), f2bf(fa0.w),
                                 f2bf(fa1.x), f2bf(fa1.y), f2bf(fa1.z), f2bf(fa1.w)};
        const bf16x8 Aq = *(const bf16x8*)aq_;

        // ---- pass 1: pos GEMM -> psc (fp32) ----
        {
            const unsigned short* pb = posB + ((size_t)lane << 3);
            int nt = w4;
            bf16x8 Bc = *(const bf16x8*)(pb + (size_t)nt * 512);
            while (nt < NT_POS) {
                const int ntn = nt + 4;
                bf16x8 Bn = Bc;
                if (ntn < NT_POS) Bn = *(const bf16x8*)(pb + (size_t)ntn * 512);
                f32x4 acc = {0.f, 0.f, 0.f, 0.f};
                acc = __builtin_amdgcn_mfma_f32_16x16x32_bf16(Aq, Bc, acc, 0, 0, 0);
                const int s = 16 * nt + n;
                if (s < S_TOT) {
                    const int h = (271 * s) >> 15;   // s/121, exact for s<512
                    const float v = (h == 0) ? acc[0] : (h == 1) ? acc[1]
                                  : (h == 2) ? acc[2] : acc[3];
                    psc[pxl][s] = v;
                }
                Bc = Bn; nt = ntn;
            }
        }
        __syncthreads();

        // ---- pass 2: union kv GEMM -> sc_bf (adds psc, one bf16 round) ----
        {
            const int r  = n & 3;
            const int co = 32 * r + 8 * quad;
            const unsigned short* kvb = pkvb
                + ((size_t)((b * PDIM + y) * PDIM) + x0) * DIM + co;
            int c = 4 * w4 + (n >> 2);     // union cell (<=15 -> i=0,u=c)
            int i = 0, u = c;
            int nt = w4;
            bf16x8 Bc = *(const bf16x8*)(kvb + (size_t)(i * PDIM + u) * DIM);
            while (nt < NT_KV) {
                // advance per-lane cell by 16 (nt += 4), clamp pad cells
                int cn = c + 16, in_ = i, un = u + 16;
                if (un >= UCOLS) { un -= UCOLS; ++in_; }
                if (cn > UCELLS - 1) { in_ = 10; un = UCOLS - 1; }
                bf16x8 Bn = Bc;
                if (nt + 4 < NT_KV)
                    Bn = *(const bf16x8*)(kvb + (size_t)(in_ * PDIM + un) * DIM);
                f32x4 acc = {0.f, 0.f, 0.f, 0.f};
                acc = __builtin_amdgcn_mfma_f32_16x16x32_bf16(Aq, Bc, acc, 0, 0, 0);
                const int jr = u - pxl;               // j_rel
                if ((unsigned)jr < 11u) {
                    const int s = 44 * i + 4 * jr + r;
                    const int h = (271 * s) >> 15;
                    const float v = ((h == 0) ? acc[0] : (h == 1) ? acc[1]
                                   : (h == 2) ? acc[2] : acc[3]) + psc[pxl][s];
                    sc_bf[pxl][s] = f2bf(v);
                }
                Bc = Bn; c = cn; i = in_; u = un; nt += 4;
            }
        }
    }
    __syncthreads();

    // ---- phase B: MFMA MLP: wave = n-tile of 16 channels, K=512 ----
    {
        const int wv   = tid >> 6;
        const int lane = tid & 63;
        const int m    = lane & 15;
        const int quad = lane >> 4;
        const unsigned short* bfr = wfrag + (((size_t)(wv * 16) * 64 + lane) << 3);
        const unsigned short* ap  = &sc_bf[m & 7][quad * 8];
        f32x4 acc = {0.f, 0.f, 0.f, 0.f};
        bf16x8 b0 = *(const bf16x8*)(bfr);
        bf16x8 b1 = *(const bf16x8*)(bfr + 512);
        bf16x8 b2 = *(const bf16x8*)(bfr + 1024);
        bf16x8 b3 = *(const bf16x8*)(bfr + 1536);
        #pragma unroll
        for (int t = 0; t < 16; ++t) {
            const bf16x8 a = *(const bf16x8*)(ap + t * 32);
            bf16x8 bn = b3;
            if (t + 4 < 16) bn = *(const bf16x8*)(bfr + (t + 4) * 512);
            acc = __builtin_amdgcn_mfma_f32_16x16x32_bf16(a, b0, acc, 0, 0, 0);
            b0 = b1; b1 = b2; b2 = b3; b3 = bn;
        }
        if (quad < 2) {
            #pragma unroll
            for (int reg = 0; reg < 4; ++reg)
                mlp[quad * 4 + reg][wv * 16 + m] = acc[reg];
        }
    }
    __syncthreads();

    // ---- epilogue: bias, exact GELU, residual ----
    for (int idx = tid; idx < TILE * DIM; idx += 512) {
        const int pix = idx >> 7, cc = idx & 127;
        const float v = mlp[pix][cc] + bias[cc];
        const float gl = 0.5f * v * (1.f + erff(v * 0.70710678118654752f));
        qs[pix][cc] += gl;               // x = q + gelu(mlp)
    }
    __syncthreads();

    // ---- LayerNorm: wave wid owns pixel wid ----
    {
        const int lane = tid & 63, wid = tid >> 6;
        const float v0 = qs[wid][lane], v1 = qs[wid][lane + 64];
        float sum = v0 + v1;
        #pragma unroll
        for (int off = 1; off < 64; off <<= 1) sum += __shfl_xor(sum, off, 64);
        const float mean = sum * (1.f / 128.f);
        const float d0 = v0 - mean, d1 = v1 - mean;
        float sq = d0 * d0 + d1 * d1;
        #pragma unroll
        for (int off = 1; off < 64; off <<= 1) sq += __shfl_xor(sq, off, 64);
        const float rstd = rsqrtf(sq * (1.f / 128.f) + LN_EPS);
        float* op = out + (size_t)(pix0 + wid) * DIM;
        op[lane]      = d0 * rstd * gam[lane]      + bet[lane];
        op[lane + 64] = d1 * rstd * gam[lane + 64] + bet[lane + 64];
    }
}

// Fallback (fp32, bounds-checked, no workspace).
__global__ __launch_bounds__(512) void nca_kernel_nopad(
    const float* __restrict__ q, const float* __restrict__ kvsrc,
    const float* __restrict__ pos, const float* __restrict__ w,
    const float* __restrict__ bias, const float* __restrict__ gam,
    const float* __restrict__ bet, float* __restrict__ out)
{
    const int tile = blockIdx.x;
    const int pix0 = tile * TILE;
    const int x0 = pix0 & 63;
    const int y  = (pix0 >> 6) & 63;
    const int b  = pix0 >> 12;
    const int tid = threadIdx.x;

    __shared__ float qs[TILE][DIM];
    __shared__ float sc[S_TOT][TILE];
    __shared__ float part[4][TILE][DIM];

    for (int i = tid; i < TILE * DIM; i += 512)
        qs[i >> 7][i & 127] = q[(size_t)pix0 * DIM + i];
    __syncthreads();

    {
        const int pix = tid >> 6;
        const int grp = (tid >> 4) & 3;
        const int l16 = tid & 15;
        const int r   = l16 >> 2;
        const int dq  = 8 * (l16 & 3);
        const int ch  = 8 * l16;
        const int xpix = x0 + pix;
        int p = grp, i = 0, j = grp;
        int h = 0, rem = 4 * grp + r;
        const float* kvb  = kvsrc + (size_t)b * IMG * IMG * DIM + ch;
        const float* posb = pos + ch;
        float4 q0 = *(const float4*)(&qs[pix][dq]);
        float4 q1 = *(const float4*)(&qs[pix][dq + 4]);
        for (int it = 0; it < 31; ++it) {
            if (p <= 120) {
                float4 k0 = make_float4(0.f,0.f,0.f,0.f), k1 = k0;
                const int ky = y + i - PAD, kx = xpix + j - PAD;
                if (((unsigned)ky < (unsigned)IMG) && ((unsigned)kx < (unsigned)IMG)) {
                    const float* kp = kvb + (size_t)(ky * IMG + kx) * DIM;
                    k0 = *(const float4*)(kp);
                    k1 = *(const float4*)(kp + 4);
                }
                const float4 p0 = *(const float4*)(posb + (size_t)p * DIM);
                const float4 p1 = *(const float4*)(posb + (size_t)p * DIM + 4);
                float t = (k0.x + p0.x) * q0.x + (k0.y + p0.y) * q0.y
                        + (k0.z + p0.z) * q0.z + (k0.w + p0.w) * q0.w
                        + (k1.x + p1.x) * q1.x + (k1.y + p1.y) * q1.y
                        + (k1.z + p1.z) * q1.z + (k1.w + p1.w) * q1.w;
                t += __shfl_xor(t, 1, 64);
                t += __shfl_xor(t, 2, 64);
                if ((l16 & 3) == 0) sc[4 * p + r][pix] = t;
            }
            p += 4; j += 4;
            if (j >= NB) { j -= NB; ++i; }
            rem += 16;
            if (rem >= NN) {
                rem -= NN; ++h;
                q0 = *(const float4*)(&qs[pix][h * 32 + dq]);
                q1 = *(const float4*)(&qs[pix][h * 32 + dq + 4]);
            }
        }
    }
    __syncthreads();

    {
        const int l  = tid & 63;
        const int wv = tid >> 6;
        const int g  = wv >> 1;
        const int ph = wv & 1;
        const float* wc  = w + (size_t)(g * NN) * DIM + l;
        const float* scp = &sc[g * NN][ph * 4];
        float a00=0,a01=0,a10=0,a11=0,a20=0,a21=0,a30=0,a31=0;
        #pragma unroll 2
        for (int s = 0; s < NN; ++s) {
            const float4 sv = *(const float4*)(scp + s * 8);
            const float w0 = wc[(size_t)s * DIM];
            const float w1 = wc[(size_t)s * DIM + 64];
            a00 += sv.x * w0; a01 += sv.x * w1;
            a10 += sv.y * w0; a11 += sv.y * w1;
            a20 += sv.z * w0; a21 += sv.z * w1;
            a30 += sv.w * w0; a31 += sv.w * w1;
        }
        const int pb = ph * 4;
        part[g][pb+0][l] = a00; part[g][pb+0][l+64] = a01;
        part[g][pb+1][l] = a10; part[g][pb+1][l+64] = a11;
        part[g][pb+2][l] = a20; part[g][pb+2][l+64] = a21;
        part[g][pb+3][l] = a30; part[g][pb+3][l+64] = a31;
    }
    __syncthreads();

    for (int idx = tid; idx < TILE * DIM; idx += 512) {
        const int pix = idx >> 7, cc = idx & 127;
        float v = part[0][pix][cc] + part[1][pix][cc]
                + part[2][pix][cc] + part[3][pix][cc] + bias[cc];
        const float gl = 0.5f * v * (1.f + erff(v * 0.70710678118654752f));
        qs[pix][cc] += gl;
    }
    __syncthreads();

    {
        const int lane = tid & 63, wid = tid >> 6;
        const float v0 = qs[wid][lane], v1 = qs[wid][lane + 64];
        float sum = v0 + v1;
        #pragma unroll
        for (int off = 1; off < 64; off <<= 1) sum += __shfl_xor(sum, off, 64);
        const float mean = sum * (1.f / 128.f);
        const float d0 = v0 - mean, d1 = v1 - mean;
        float sq = d0 * d0 + d1 * d1;
        #pragma unroll
        for (int off = 1; off < 64; off <<= 1) sq += __shfl_xor(sq, off, 64);
        const float rstd = rsqrtf(sq * (1.f / 128.f) + LN_EPS);
        float* op = out + (size_t)(pix0 + wid) * DIM;
        op[lane]      = d0 * rstd * gam[lane]      + bet[lane];
        op[lane + 64] = d1 * rstd * gam[lane + 64] + bet[lane + 64];
    }
}

extern "C" void kernel_launch(void* const* d_in, const int* in_sizes, int n_in,
                              void* d_out, int out_size, void* d_ws, size_t ws_size,
                              hipStream_t stream) {
    const float* q    = (const float*)d_in[0];
    const float* kv   = (const float*)d_in[1];
    const float* pos  = (const float*)d_in[2];
    const float* w    = (const float*)d_in[3];
    const float* bias = (const float*)d_in[4];
    const float* gam  = (const float*)d_in[5];
    const float* bet  = (const float*)d_in[6];
    float* out = (float*)d_out;

    const int n_blocks = 2 * IMG * IMG / TILE;   // 1024
    const size_t pkvb_bytes  = (size_t)2 * PDIM * PDIM * DIM * sizeof(unsigned short); // 2,803,712
    const size_t wfrag_bytes = (size_t)8 * 16 * 64 * 8 * sizeof(unsigned short);       // 131,072
    const size_t posB_bytes  = (size_t)NT_POS * 64 * 8 * sizeof(unsigned short);       // 31,744

    if (ws_size >= pkvb_bytes + wfrag_bytes + posB_bytes) {
        unsigned short* pkvb  = (unsigned short*)d_ws;
        unsigned short* wfrag = (unsigned short*)((char*)d_ws + pkvb_bytes);
        unsigned short* posB  = (unsigned short*)((char*)d_ws + pkvb_bytes + wfrag_bytes);
        const int prep_blocks = KVB + 32 + (NT_POS + 3) / 4;   // 2738+32+8
        prep_kernel<<<prep_blocks, 256, 0, stream>>>(kv, w, pos, pkvb, wfrag, posB);
        nca_kernel<<<n_blocks, 512, 0, stream>>>(q, pkvb, posB, wfrag, bias, gam, bet, out);
    } else {
        nca_kernel_nopad<<<n_blocks, 512, 0, stream>>>(q, kv, pos, w, bias, gam, bet, out);
    }
}